// Round 6
// baseline (136.595 us; speedup 1.0000x reference)
//
#include <hip/hip_runtime.h>
#include <hip/hip_bf16.h>
#include <math.h>

#define B_   8
#define C_   192
#define N_   3136
#define K_   9
#define OUT_ 384
#define G_   4
#define CG_  96   // in-channels per group (2C/G)
#define OG_  96   // out-channels per group
#define NT_  16   // n-rows per fused block
#define NTB_ 196  // N_/NT_
#define LDW  196  // LDS row width in dwords (192 data + 4 pad)

typedef __attribute__((ext_vector_type(8))) short short8;
typedef __attribute__((ext_vector_type(4))) float floatx4;

// ---------------- ws layout (bytes) ----------------
// xT  : B*N*C   bf16      =  9,633,792
// y   : B*OUT*N bf16      = 19,267,584
// sp  : B*196*4*192 f32   =  4,816,896  (per-tile per-group BN partials)
// wsw : OUT*CG bf16       =     73,728  (fragment-order swizzled weights)
// st  : OUT*2 f32
static const size_t OFF_XT  = 0;
static const size_t OFF_Y   = 9633792;
static const size_t OFF_SP  = OFF_Y  + 19267584;   // 28,901,376
static const size_t OFF_WSW = OFF_SP + 4816896;    // 33,718,272 (16B aligned)
static const size_t OFF_ST  = OFF_WSW + 73728;

__device__ inline short f2bs(float f) {
    __hip_bfloat16 h = __float2bfloat16(f);
    union { __hip_bfloat16 h; short s; } u; u.h = h; return u.s;
}
__device__ inline float blo(unsigned int u) {
    unsigned int v = u << 16; return __builtin_bit_cast(float, v);
}
__device__ inline float bhi(unsigned int u) {
    unsigned int v = u & 0xffff0000u; return __builtin_bit_cast(float, v);
}
__device__ inline unsigned int packbf(float lo, float hi) {
    unsigned int l = (unsigned int)(unsigned short)f2bs(lo);
    unsigned int h = (unsigned int)(unsigned short)f2bs(hi);
    return (h << 16) | l;
}

// ---- Kernel A: transpose x -> xT bf16; fold W -> fragment-order bf16 ----
// wsw layout: frag f = (g*6+mt)*3+kc (72 frags of 512 shorts);
//             within frag: lane*8 + j, lane = quad*16+col
// so a wave's short8 fragment load is one contiguous, coalesced 1 KB read.
__global__ __launch_bounds__(256) void k_transpose(const float* __restrict__ x,
                                                   __hip_bfloat16* __restrict__ xT,
                                                   const float* __restrict__ w,
                                                   __hip_bfloat16* __restrict__ wsw) {
    if (blockIdx.y == 0) {
        int j = blockIdx.x * 49 + blockIdx.z;   // 392 candidate blocks, use 144
        if (j < 144) {
            int i = j * 256 + threadIdx.x;      // 0..36863
            int oc = i / CG_, cg = i - oc * CG_;
            int g = oc / OG_, ocl = oc - g * OG_;
            int mt = ocl >> 4, col = ocl & 15;
            int kc = cg >> 5, rem = cg & 31;
            int qd = rem >> 3, jj = rem & 7;
            int dst = (((g * 6 + mt) * 3 + kc) * 64 + qd * 16 + col) * 8 + jj;
            wsw[dst] = __float2bfloat16(w[i]);
        }
    }
    __shared__ float tile[64][65];
    int b  = blockIdx.x;
    int cb = blockIdx.y * 64;
    int nb = blockIdx.z * 64;
    int tid = threadIdx.x;
    int tn  = tid & 63;
    int tc4 = tid >> 6;
    const float* xp = x + ((size_t)b * C_ + cb) * N_ + nb;
    #pragma unroll
    for (int i = 0; i < 16; ++i) {
        int c = tc4 + i * 4;
        tile[c][tn] = xp[(size_t)c * N_ + tn];
    }
    __syncthreads();
    __hip_bfloat16* xo = xT + ((size_t)b * N_ + nb) * C_ + cb;
    int tcl = tid & 63;
    int tn4 = tid >> 6;
    #pragma unroll
    for (int i = 0; i < 16; ++i) {
        int n = tn4 + i * 4;
        xo[(size_t)n * C_ + tcl] = __float2bfloat16(tile[tcl][n]);
    }
}

// ---- Kernel B: FUSED gather + max-rel (LDS) + grouped MFMA conv + BN partials ----
// Block: 16 n-rows. Phase 1: 8 half-waves gather 2 rows each into LDS xc tile.
// Phase 2: wave g computes group g (96 oc x 16 n), writes y + its own sp slice.
__global__ __launch_bounds__(256) void k_fconv(const __hip_bfloat16* __restrict__ xT,
                                               const int* __restrict__ eidx,
                                               const __hip_bfloat16* __restrict__ wsw,
                                               const float* __restrict__ bias,
                                               __hip_bfloat16* __restrict__ y,
                                               float* __restrict__ sp) {
    int b  = blockIdx.x;
    int nt = blockIdx.y;
    int n0 = nt * NT_;
    int tid  = threadIdx.x;
    int half = tid >> 5;
    int cd   = tid & 31;

    __shared__ unsigned int xcs[NT_ * LDW];   // 12,544 B

    const unsigned int* xb = reinterpret_cast<const unsigned int*>(xT + (size_t)b * N_ * C_);
    #pragma unroll
    for (int p = 0; p < 2; ++p) {
        int rl = half + p * 8;                // local row 0..15
        int n  = n0 + rl;
        const int* e0 = eidx + ((size_t)b * N_ + n) * K_;
        const int* e1 = eidx + (size_t)B_ * N_ * K_ + ((size_t)b * N_ + n) * K_;
        int o0[K_], o1[K_];
        #pragma unroll
        for (int k = 0; k < K_; ++k) { o0[k] = e0[k] * (C_ / 2); o1[k] = e1[k] * (C_ / 2); }
        const unsigned int* xn = xb + (size_t)n * (C_ / 2);
        #pragma unroll
        for (int it = 0; it < 3; ++it) {
            int c2 = cd + it * 32;
            unsigned int ctr = xn[c2];
            float r0 = -INFINITY, r1 = -INFINITY;
            #pragma unroll
            for (int k = 0; k < K_; ++k) {
                unsigned int uj = xb[(size_t)o0[k] + c2];
                unsigned int ui = xb[(size_t)o1[k] + c2];
                r0 = fmaxf(r0, blo(uj) - blo(ui));
                r1 = fmaxf(r1, bhi(uj) - bhi(ui));
            }
            uint2 o;
            o.x = packbf(blo(ctr), r0);
            o.y = packbf(bhi(ctr), r1);
            *reinterpret_cast<uint2*>(&xcs[rl * LDW + 2 * c2]) = o;
        }
    }
    __syncthreads();

    int lane = tid & 63;
    int g    = tid >> 6;                       // wave id == conv group
    int col  = lane & 15;
    int quad = lane >> 4;

    const short* xs = reinterpret_cast<const short*>(xcs);
    short8 bfr[3];
    #pragma unroll
    for (int kc = 0; kc < 3; ++kc)
        bfr[kc] = *reinterpret_cast<const short8*>(
            xs + col * (LDW * 2) + g * CG_ + kc * 32 + quad * 8);

    const short* ws = reinterpret_cast<const short*>(wsw);
    floatx4 acc[6];
    #pragma unroll
    for (int mt = 0; mt < 6; ++mt) acc[mt] = (floatx4){0.f, 0.f, 0.f, 0.f};
    #pragma unroll
    for (int kc = 0; kc < 3; ++kc) {
        #pragma unroll
        for (int mt = 0; mt < 6; ++mt) {
            short8 wf = *reinterpret_cast<const short8*>(
                ws + (((g * 6 + mt) * 3 + kc) << 9) + (lane << 3));
            acc[mt] = __builtin_amdgcn_mfma_f32_16x16x32_bf16(wf, bfr[kc], acc[mt], 0, 0, 0);
        }
    }

    // epilogue: bias, y write, per-wave BN partials (waves own disjoint oc)
    size_t spb = (((size_t)b * NTB_ + nt) * G_ + g) * 192;
    #pragma unroll
    for (int mt = 0; mt < 6; ++mt) {
        #pragma unroll
        for (int r = 0; r < 4; ++r) {
            int ol = mt * 16 + quad * 4 + r;   // oc within group
            int oc = g * OG_ + ol;
            float v = acc[mt][r] + bias[oc];
            y[((size_t)b * OUT_ + oc) * N_ + n0 + col] = __float2bfloat16(v);
            float s = v, ss = v * v;
            #pragma unroll
            for (int m = 1; m <= 8; m <<= 1) {
                s  += __shfl_xor(s, m);
                ss += __shfl_xor(ss, m);
            }
            if (col == 0) {
                sp[spb + ol]      = s;
                sp[spb + 96 + ol] = ss;
            }
        }
    }
}

// ---- Kernel C: fold per-tile partials into st[OUT*2] ----
__global__ __launch_bounds__(256) void k_redstats(const float* __restrict__ sp,
                                                  float* __restrict__ st) {
    int oc = blockIdx.x;
    int g  = oc / OG_;
    int o  = oc % OG_;
    float s = 0.f, ss = 0.f;
    for (int e = threadIdx.x; e < B_ * NTB_; e += 256) {
        const float* p = sp + ((size_t)e * G_ + g) * 192;
        s  += p[o];
        ss += p[96 + o];
    }
    #pragma unroll
    for (int m = 32; m; m >>= 1) {
        s  += __shfl_xor(s, m);
        ss += __shfl_xor(ss, m);
    }
    __shared__ float ls[4], lss[4];
    int wid = threadIdx.x >> 6, lane = threadIdx.x & 63;
    if (lane == 0) { ls[wid] = s; lss[wid] = ss; }
    __syncthreads();
    if (threadIdx.x == 0) {
        st[oc]        = ls[0] + ls[1] + ls[2] + ls[3];
        st[OUT_ + oc] = lss[0] + lss[1] + lss[2] + lss[3];
    }
}

// ---- Kernel D: BN (batch stats) + exact GELU, write fp32 out [B,OUT,N] ----
__global__ __launch_bounds__(256) void k_bn_gelu(const __hip_bfloat16* __restrict__ y,
                                                 const float* __restrict__ st,
                                                 const float* __restrict__ gamma,
                                                 const float* __restrict__ beta,
                                                 float* __restrict__ out) {
    size_t base = ((size_t)blockIdx.x * 256 + threadIdx.x) * 4;
    int oc = (int)((base / N_) % OUT_);
    const float invM = 1.0f / (float)(B_ * N_);
    float s = st[oc], ss = st[OUT_ + oc];
    float mean = s * invM;
    float var  = ss * invM - mean * mean;
    float inv  = 1.0f / sqrtf(var + 1e-5f);
    float sc = gamma[oc] * inv;
    float sh = beta[oc] - mean * sc;

    const __hip_bfloat162* yp = reinterpret_cast<const __hip_bfloat162*>(y + base);
    __hip_bfloat162 p0 = yp[0], p1 = yp[1];
    float v[4] = { __bfloat162float(p0.x), __bfloat162float(p0.y),
                   __bfloat162float(p1.x), __bfloat162float(p1.y) };
    float4 o;
    float* op = &o.x;
    #pragma unroll
    for (int j = 0; j < 4; ++j) {
        float t = v[j] * sc + sh;
        op[j] = 0.5f * t * (1.0f + erff(t * 0.70710678118654752f));
    }
    *reinterpret_cast<float4*>(out + base) = o;
}

extern "C" void kernel_launch(void* const* d_in, const int* in_sizes, int n_in,
                              void* d_out, int out_size, void* d_ws, size_t ws_size,
                              hipStream_t stream) {
    const float* x      = (const float*)d_in[0];
    const int*   eidx   = (const int*)d_in[1];
    const float* conv_w = (const float*)d_in[2];
    const float* conv_b = (const float*)d_in[3];
    const float* gamma  = (const float*)d_in[4];
    const float* beta   = (const float*)d_in[5];
    float* out = (float*)d_out;

    char* ws = (char*)d_ws;
    __hip_bfloat16* xT  = (__hip_bfloat16*)(ws + OFF_XT);
    __hip_bfloat16* y   = (__hip_bfloat16*)(ws + OFF_Y);
    float*          sp  = (float*)(ws + OFF_SP);
    __hip_bfloat16* wsw = (__hip_bfloat16*)(ws + OFF_WSW);
    float*          st  = (float*)(ws + OFF_ST);

    k_transpose<<<dim3(B_, C_ / 64, N_ / 64), 256, 0, stream>>>(x, xT, conv_w, wsw);
    k_fconv<<<dim3(B_, NTB_), 256, 0, stream>>>(xT, eidx, wsw, conv_b, y, sp);
    k_redstats<<<OUT_, 256, 0, stream>>>(sp, st);
    k_bn_gelu<<<dim3((B_ * OUT_ * N_) / (256 * 4)), 256, 0, stream>>>(y, st, gamma, beta, out);
}